// Round 11
// baseline (230.711 us; speedup 1.0000x reference)
//
#include <hip/hip_runtime.h>

#define DEV static __device__ __forceinline__

typedef __attribute__((ext_vector_type(8))) short short8;
typedef __attribute__((ext_vector_type(4))) short short4v;
typedef __attribute__((ext_vector_type(4))) float f32x4;
typedef __attribute__((ext_vector_type(4))) unsigned short ushort4v;
typedef __attribute__((ext_vector_type(4))) float float4v;

#define DM 1024
#define NH 16
#define HD 64
#define SS 2048
#define TOK 8192

DEV unsigned short f2bf(float f) {
  union { float f; unsigned u; } v; v.f = f;
  unsigned r = v.u + 0x7FFFu + ((v.u >> 16) & 1u);
  return (unsigned short)(r >> 16);
}
DEV float bf2f(unsigned short h) {
  union { unsigned u; float f; } v; v.u = ((unsigned)h) << 16;
  return v.f;
}

#define MFMA16x32(a, b, c) __builtin_amdgcn_mfma_f32_16x16x32_bf16((a), (b), (c), 0, 0, 0)

DEV f32x4 mfma_pv(short4v a, short4v b, f32x4 c) {
#if __has_builtin(__builtin_amdgcn_mfma_f32_16x16x16bf16_1k)
  return __builtin_amdgcn_mfma_f32_16x16x16bf16_1k(a, b, c, 0, 0, 0);
#else
  f32x4 d;
  asm("v_mfma_f32_16x16x16_bf16 %0, %1, %2, %3" : "=&v"(d) : "v"(a), "v"(b), "v"(c));
  return d;
#endif
}

DEV void gload_lds16(const unsigned short* g, unsigned short* l) {
  __builtin_amdgcn_global_load_lds(
      (const __attribute__((address_space(1))) void*)g,
      (__attribute__((address_space(3))) void*)l, 16, 0, 0);
}

// ---------------- fp32 -> bf16 convert ----------------
__global__ __launch_bounds__(256) void k_cvt(const float* __restrict__ in,
                                             unsigned short* __restrict__ out, int n4) {
  int i = blockIdx.x * 256 + threadIdx.x;
  if (i >= n4) return;
  float4v v = ((const float4v*)in)[i];
  ushort4v o;
  o[0] = f2bf(v[0]); o[1] = f2bf(v[1]); o[2] = f2bf(v[2]); o[3] = f2bf(v[3]);
  ((ushort4v*)out)[i] = o;
}

// ---------------- RoPE cos/sin table: [B*S][32] ----------------
__global__ __launch_bounds__(256) void k_tab(const int* __restrict__ pos,
                                             float* __restrict__ tc, float* __restrict__ ts) {
  int i = blockIdx.x * 256 + threadIdx.x;   // B*S*32 total
  int t = i >> 5, fi = i & 31;
  float p = (float)pos[t];
  float inv = powf(10000.0f, -(float)fi / 32.0f);
  float a = p * inv;
  float sv, cv;
  sincosf(a, &sv, &cv);
  tc[i] = cv;
  ts[i] = sv;
}

// ---------------- bf16 GEMM #1: 256x256x32, 4-buffer counted-vmcnt ----------
// C[m][n] = sum_k A[m][k]*B[n][k] + bias[n].  BM=BN=256, BK=32.
// 512 threads = 8 waves (2 Mrows x 4 Ncols), per-wave output 128x64
// (acc 8x4 frags = 128 VGPR; __launch_bounds__(512,2) pins <=256 VGPR).
// Intensity 128 FLOP/staged-byte (vs 85 at 256x128) -> per-CU L2 demand
// ~26 B/cy at FULL MFMA rate, under the ~56 B/cy fair share.
// 4 rotating LDS buffers (4 x 32KB = 128 KB): iter t computes buf[t&3],
// stages tile t+3 into buf[(t+3)&3] (= buf[(t-1)&3], readers passed the
// end-of-iter-t-1 barrier). End-of-iter wait vmcnt(8) leaves tiles
// {t+2,t+3} in flight -> tile t+1 complete; prefetch horizon >= 2 full
// iterations (~5000 cy >> 900 cy HBM). Never drains in-loop.
// Fragment-contiguous LDS cells: every gload_lds dest and ds_read_b128 is
// base + lane*16 (conflict-free, measured 0 since R6).
// m-chunk XCD swizzle (R6/R10-proven): A slab per XCD = 2 MB, L2-fit.
// MODE 0: out0 = fp32 [M][N]
// MODE 1: qkv scatter + FUSED ROPE on Q,K (same epilogue as R10).
template <int MODE>
__global__ __launch_bounds__(512, 2) void k_gemm6(
    const unsigned short* __restrict__ A, const unsigned short* __restrict__ Bm,
    const float* __restrict__ bias, void* __restrict__ out0, void* __restrict__ out1,
    void* __restrict__ out2, const float* __restrict__ tabc,
    const float* __restrict__ tabs, int M, int N, int K) {
  __shared__ __align__(16) unsigned short Abuf[4][8192];   // 4 x 16 KB
  __shared__ __align__(16) unsigned short Bbuf[4][8192];   // 4 x 16 KB
  const int tid = threadIdx.x;
  const int wid = tid >> 6, lane = tid & 63;
  const int l16 = lane & 15, lq = lane >> 4;
  const int wm = wid >> 2, wn = wid & 3;      // 2 M x 4 N
  const int NT = K >> 5;

  // m-chunk XCD swizzle (nwg % 8 == 0: 384 ok)
  const int gx = N >> 8;
  const int nwg = gx * (M >> 8);
  const int chunk = nwg >> 3;
  const int bid = blockIdx.x;
  const int virt = (bid & 7) * chunk + (bid >> 3);
  const int m0 = (virt / gx) << 8;
  const int n0 = (virt % gx) << 8;

  // A tile: 1024 cells of 16B ([mf 0..15][kc 0..3][l16]); 2 loads/thread.
  // B identical. 4 gload_lds per thread per tile.
#define STAGE_G6(T, BSEL)                                                        \
  {                                                                              \
    int k0_ = (T) << 5;                                                          \
    unsigned short* ab_ = Abuf[BSEL];                                            \
    unsigned short* bb_ = Bbuf[BSEL];                                            \
    _Pragma("unroll")                                                            \
    for (int i_ = 0; i_ < 2; ++i_) {                                             \
      int c_ = tid + (i_ << 9);                                                  \
      int l_ = c_ & 15, kc_ = (c_ >> 4) & 3, mf_ = c_ >> 6;                      \
      gload_lds16(A + (size_t)(m0 + mf_ * 16 + l_) * K + k0_ + kc_ * 8,          \
                  &ab_[c_ * 8]);                                                 \
      gload_lds16(Bm + (size_t)(n0 + mf_ * 16 + l_) * K + k0_ + kc_ * 8,         \
                  &bb_[c_ * 8]);                                                 \
    }                                                                            \
  }

  f32x4 acc[8][4];
#pragma unroll
  for (int i = 0; i < 8; i++)
#pragma unroll
    for (int j = 0; j < 4; j++) acc[i][j] = (f32x4){0.f, 0.f, 0.f, 0.f};

  // prologue: tiles 0,1,2 in flight (12 loads); wait tile 0 (8 outstanding)
  STAGE_G6(0, 0)
  STAGE_G6(1, 1)
  STAGE_G6(2, 2)
  asm volatile("s_waitcnt vmcnt(8)" ::: "memory");
  __builtin_amdgcn_s_barrier();
  __builtin_amdgcn_sched_barrier(0);

  for (int t = 0; t < NT; ++t) {
    const int cb = t & 3;
    if (t + 3 < NT) { STAGE_G6(t + 3, (t + 3) & 3) }
    const unsigned short* Ab = Abuf[cb];
    const unsigned short* Bb = Bbuf[cb];
    short8 af[8], bf[4];
#pragma unroll
    for (int mi = 0; mi < 8; ++mi)
      af[mi] = *(const short8*)&Ab[(((wm * 8 + mi) * 4 + lq) * 16 + l16) * 8];
#pragma unroll
    for (int ni = 0; ni < 4; ++ni)
      bf[ni] = *(const short8*)&Bb[(((wn * 4 + ni) * 4 + lq) * 16 + l16) * 8];
#pragma unroll
    for (int mi = 0; mi < 8; ++mi)
#pragma unroll
      for (int ni = 0; ni < 4; ++ni)
        acc[mi][ni] = MFMA16x32(af[mi], bf[ni], acc[mi][ni]);
    if (t + 1 < NT) {
      if (t + 4 <= NT) {        // tiles {t+2,t+3} may stay in flight
        asm volatile("s_waitcnt vmcnt(8)" ::: "memory");
      } else if (t + 3 <= NT) { // only {t+2}
        asm volatile("s_waitcnt vmcnt(4)" ::: "memory");
      } else {
        asm volatile("s_waitcnt vmcnt(0)" ::: "memory");
      }
      __builtin_amdgcn_s_barrier();
      __builtin_amdgcn_sched_barrier(0);
    }
  }
#undef STAGE_G6

  if (MODE == 0) {
    float* C = (float*)out0;
#pragma unroll
    for (int mi = 0; mi < 8; ++mi) {
      int row = m0 + wm * 128 + mi * 16 + lq * 4;
#pragma unroll
      for (int ni = 0; ni < 4; ++ni) {
        int col = n0 + wn * 64 + ni * 16 + l16;
        float bv = bias[col];
#pragma unroll
        for (int j = 0; j < 4; ++j)
          C[(size_t)(row + j) * N + col] = acc[mi][ni][j] + bv;
      }
    }
  } else {
    unsigned short* Qb = (unsigned short*)out0;
    unsigned short* Kb = (unsigned short*)out1;
    unsigned short* Vt = (unsigned short*)out2;
    int sel0 = n0 >> 10;   // block spans 256 cols inside one 1024-wide section
#pragma unroll
    for (int mi = 0; mi < 8; ++mi) {
      int row = m0 + wm * 128 + mi * 16 + lq * 4;   // token index base
#pragma unroll
      for (int ni = 0; ni < 4; ++ni) {
        int col = n0 + wn * 64 + ni * 16 + l16;
        int hh = (col >> 6) & 15;
        int d = col & 63;
        float bv = bias[col];
        if (sel0 < 2) {
          // fused RoPE: pair partner at lane^1 (col^1), sign by d parity
          unsigned short* P = sel0 ? Kb : Qb;
          int pfr = d >> 1;
          size_t p = ((size_t)((row >> 11) * NH + hh) * SS + (row & 2047)) * 64 + d;
#pragma unroll
          for (int j = 0; j < 4; ++j) {
            float val = acc[mi][ni][j] + bv;
            float part = __shfl_xor(val, 1, 64);
            int rr = row + j;                       // token index
            float cv = tabc[((size_t)rr << 5) + pfr];
            float sv = tabs[((size_t)rr << 5) + pfr];
            float outv = (d & 1) ? (part * sv + val * cv)
                                 : (val * cv - part * sv);
            P[p + (size_t)j * 64] = f2bf(outv);
          }
        } else {
          size_t p = ((size_t)((row >> 11) * NH + hh) * 64 + d) * SS + (row & 2047);
          ushort4v o;
#pragma unroll
          for (int j = 0; j < 4; ++j) o[j] = f2bf(acc[mi][ni][j] + bv);
          *(ushort4v*)&Vt[p] = o;
        }
      }
    }
  }
}

// ---------------- bf16 GEMM #2 (R6 skeleton, 256x128x64, 3-buffer) ----------
// Unchanged from R10 (measured ~28 us for the Wo projection).
template <int MODE>
__global__ __launch_bounds__(512) void k_gemm3(
    const unsigned short* __restrict__ A, const unsigned short* __restrict__ Bm,
    const float* __restrict__ bias, void* __restrict__ out0, void* __restrict__ out1,
    void* __restrict__ out2, const float* __restrict__ tabc,
    const float* __restrict__ tabs, int M, int N, int K) {
  __shared__ __align__(16) unsigned short Abuf[3][256 * 64];   // 96 KB
  __shared__ __align__(16) unsigned short Bbuf[3][128 * 64];   // 48 KB
  const int tid = threadIdx.x;
  const int wid = tid >> 6, lane = tid & 63;
  const int l16 = lane & 15, lq = lane >> 4;
  const int wr = wid >> 1, wc = wid & 1;
  const int r8 = lane >> 3, c8 = lane & 7;    // staging: row-in-octet, chunk
  const int NT = K >> 6;
  const int sx = l16 & 7;                     // read-side swizzle key

  const int gx = N >> 7;
  const int nwg = gx * (M >> 8);
  const int chunk = nwg >> 3;
  const int bid = blockIdx.x;
  const int virt = (bid & 7) * chunk + (bid >> 3);
  const int m0 = (virt / gx) << 8;
  const int n0 = (virt % gx) << 7;

#define STAGE_G3(T, BSEL)                                                           \
  {                                                                                 \
    int k0_ = (T) << 6;                                                             \
    unsigned short* ab_ = Abuf[BSEL];                                               \
    unsigned short* bb_ = Bbuf[BSEL];                                               \
    _Pragma("unroll")                                                               \
    for (int i_ = 0; i_ < 4; ++i_) {                                                \
      int c_ = wid * 4 + i_;                                                        \
      gload_lds16(A + (size_t)(m0 + c_ * 8 + r8) * K + k0_ + ((c8 ^ r8) << 3),      \
                  &ab_[c_ * 512]);                                                  \
    }                                                                               \
    _Pragma("unroll")                                                               \
    for (int i_ = 0; i_ < 2; ++i_) {                                                \
      int c_ = wid * 2 + i_;                                                        \
      gload_lds16(Bm + (size_t)(n0 + c_ * 8 + r8) * K + k0_ + ((c8 ^ r8) << 3),     \
                  &bb_[c_ * 512]);                                                  \
    }                                                                               \
  }

  f32x4 acc[4][4];
#pragma unroll
  for (int i = 0; i < 4; i++)
#pragma unroll
    for (int j = 0; j < 4; j++) acc[i][j] = (f32x4){0.f, 0.f, 0.f, 0.f};

  STAGE_G3(0, 0)
  STAGE_G3(1, 1)
  asm volatile("s_waitcnt vmcnt(6)" ::: "memory");
  __builtin_amdgcn_s_barrier();
  __builtin_amdgcn_sched_barrier(0);

  int cb = 0, sb = 2;
  for (int t = 0; t < NT; ++t) {
    if (t + 2 < NT) STAGE_G3(t + 2, sb)
    const unsigned short* Ab = Abuf[cb];
    const unsigned short* Bb = Bbuf[cb];
#pragma unroll
    for (int kk = 0; kk < 2; ++kk) {
      int sw0 = ((kk * 4 + lq) ^ sx) << 3;
      short8 af[4], bfr[4];
#pragma unroll
      for (int mi = 0; mi < 4; ++mi)
        af[mi] = *(const short8*)&Ab[(wr * 64 + mi * 16 + l16) * 64 + sw0];
#pragma unroll
      for (int ni = 0; ni < 4; ++ni)
        bfr[ni] = *(const short8*)&Bb[(wc * 64 + ni * 16 + l16) * 64 + sw0];
#pragma unroll
      for (int mi = 0; mi < 4; ++mi)
#pragma unroll
        for (int ni = 0; ni < 4; ++ni)
          acc[mi][ni] = MFMA16x32(af[mi], bfr[ni], acc[mi][ni]);
    }
    if (t + 1 < NT) {
      if (t + 3 <= NT) {
        asm volatile("s_waitcnt vmcnt(6)" ::: "memory");
      } else {
        asm volatile("s_waitcnt vmcnt(0)" ::: "memory");
      }
      __builtin_amdgcn_s_barrier();
      __builtin_amdgcn_sched_barrier(0);
    }
    cb = (cb == 2) ? 0 : cb + 1;
    sb = (sb == 2) ? 0 : sb + 1;
  }
#undef STAGE_G3

  if (MODE == 0) {
    float* C = (float*)out0;
#pragma unroll
    for (int mi = 0; mi < 4; ++mi) {
      int row = m0 + wr * 64 + mi * 16 + lq * 4;
#pragma unroll
      for (int ni = 0; ni < 4; ++ni) {
        int col = n0 + wc * 64 + ni * 16 + l16;
        float bv = bias[col];
#pragma unroll
        for (int j = 0; j < 4; ++j)
          C[(size_t)(row + j) * N + col] = acc[mi][ni][j] + bv;
      }
    }
  } else {
    unsigned short* Qb = (unsigned short*)out0;
    unsigned short* Kb = (unsigned short*)out1;
    unsigned short* Vt = (unsigned short*)out2;
    int sel0 = n0 >> 10;
#pragma unroll
    for (int mi = 0; mi < 4; ++mi) {
      int row = m0 + wr * 64 + mi * 16 + lq * 4;
#pragma unroll
      for (int ni = 0; ni < 4; ++ni) {
        int col = n0 + wc * 64 + ni * 16 + l16;
        int hh = (col >> 6) & 15;
        int d = col & 63;
        float bv = bias[col];
        if (sel0 < 2) {
          unsigned short* P = sel0 ? Kb : Qb;
          int pfr = d >> 1;
          size_t p = ((size_t)((row >> 11) * NH + hh) * SS + (row & 2047)) * 64 + d;
#pragma unroll
          for (int j = 0; j < 4; ++j) {
            float val = acc[mi][ni][j] + bv;
            float part = __shfl_xor(val, 1, 64);
            int rr = row + j;
            float cv = tabc[((size_t)rr << 5) + pfr];
            float sv = tabs[((size_t)rr << 5) + pfr];
            float outv = (d & 1) ? (part * sv + val * cv)
                                 : (val * cv - part * sv);
            P[p + (size_t)j * 64] = f2bf(outv);
          }
        } else {
          size_t p = ((size_t)((row >> 11) * NH + hh) * 64 + d) * SS + (row & 2047);
          ushort4v o;
#pragma unroll
          for (int j = 0; j < 4; ++j) o[j] = f2bf(acc[mi][ni][j] + bv);
          *(ushort4v*)&Vt[p] = o;
        }
      }
    }
  }
}

// ---------------- causal flash attention (unchanged from R10) ----------------
__global__ __launch_bounds__(256) void k_attn(const unsigned short* __restrict__ Q,
                                              const unsigned short* __restrict__ K,
                                              const unsigned short* __restrict__ Vt,
                                              unsigned short* __restrict__ H) {
  __shared__ __align__(16) unsigned short Kbuf[2 * 4096];
  __shared__ __align__(16) unsigned short Vbuf[2 * 4096];

  int lin = blockIdx.x;          // 1024 blocks; lin%8 spreads heads over XCDs
  int bh = lin & 63;
  int p = lin >> 6;              // 0..15 granule pair
  int b = bh >> 4, h = bh & 15;
  int wid = threadIdx.x >> 6, lane = threadIdx.x & 63;
  int l16 = lane & 15, lq = lane >> 4;
  int sx = l16 & 7;              // read-side swizzle key (row&7)
  const unsigned short* Qh = Q + (size_t)bh * SS * 64;
  const unsigned short* Kh = K + (size_t)bh * SS * 64;
  const unsigned short* Vh = Vt + (size_t)bh * 64 * SS;

  for (int seg = 0; seg < 2; ++seg) {
    int g = seg ? (31 - p) : p;               // granule 0..31 (64 q-rows)
    int qbase = g * 64 + wid * 16;            // this wave's first q-row
    int qrow = qbase + l16;                   // this lane's q-row
    int ntk = g + 1;

    short8 aq[2];
    {
      const unsigned short* qp = Qh + (size_t)qrow * 64 + lq * 8;
      aq[0] = *(const short8*)qp;
      aq[1] = *(const short8*)(qp + 32);
    }
    f32x4 o[4];
#pragma unroll
    for (int i = 0; i < 4; ++i) o[i] = (f32x4){0.f, 0.f, 0.f, 0.f};
    float lsum = 0.f;

#pragma unroll
    for (int i = 0; i < 2; ++i) {
      int c = threadIdx.x + (i << 8);
      int row = c >> 3, col = ((c & 7) ^ (row & 7)) << 3;
      gload_lds16(Kh + (size_t)row * 64 + col, &Kbuf[c * 8]);
      gload_lds16(Vh + (size_t)row * SS + col, &Vbuf[c * 8]);
    }
    __syncthreads();

    int cur = 0;
    for (int kt = 0; kt < ntk; ++kt) {
      if (kt + 1 < ntk) {
        int kb1 = (kt + 1) << 6;
        int nb_ = (cur ^ 1) * 4096;
#pragma unroll
        for (int i = 0; i < 2; ++i) {
          int c = threadIdx.x + (i << 8);
          int row = c >> 3, col = ((c & 7) ^ (row & 7)) << 3;
          gload_lds16(Kh + (size_t)(kb1 + row) * 64 + col, &Kbuf[nb_ + c * 8]);
          gload_lds16(Vh + (size_t)row * SS + kb1 + col, &Vbuf[nb_ + c * 8]);
        }
      }
      int kb = kt << 6;
      const unsigned short* Kb_ = &Kbuf[cur * 4096];
      const unsigned short* Vb_ = &Vbuf[cur * 4096];

      f32x4 sacc[4];
#pragma unroll
      for (int nb = 0; nb < 4; ++nb) {
        int r = nb * 16 + l16;
        short8 bk0 = *(const short8*)&Kb_[r * 64 + ((lq ^ sx) << 3)];
        short8 bk1 = *(const short8*)&Kb_[r * 64 + (((4 | lq) ^ sx) << 3)];
        f32x4 z = (f32x4){0.f, 0.f, 0.f, 0.f};
        z = MFMA16x32(bk0, aq[0], z);
        z = MFMA16x32(bk1, aq[1], z);
        sacc[nb] = z;
      }
      float sc[4][4];
#pragma unroll
      for (int nb = 0; nb < 4; ++nb)
#pragma unroll
        for (int j = 0; j < 4; ++j) sc[nb][j] = sacc[nb][j] * 0.18033688f;
      if (kt == g) {
#pragma unroll
        for (int nb = 0; nb < 4; ++nb)
#pragma unroll
          for (int j = 0; j < 4; ++j) {
            int key = kb + nb * 16 + lq * 4 + j;
            if (key > qrow) sc[nb][j] = -1e30f;
          }
      }
      short4v pa[4];
#pragma unroll
      for (int nb = 0; nb < 4; ++nb) {
        float pv[4];
#pragma unroll
        for (int j = 0; j < 4; ++j) {
          float e;
          asm("v_exp_f32 %0, %1" : "=v"(e) : "v"(sc[nb][j]));
          lsum += e;
          pv[j] = e;
        }
        union { unsigned u[2]; short4v s4; } pk;
        asm("v_cvt_pk_bf16_f32 %0, %1, %2" : "=v"(pk.u[0]) : "v"(pv[0]), "v"(pv[1]));
        asm("v_cvt_pk_bf16_f32 %0, %1, %2" : "=v"(pk.u[1]) : "v"(pv[2]), "v"(pv[3]));
        pa[nb] = pk.s4;
      }
#pragma unroll
      for (int ni = 0; ni < 4; ++ni) {
        int row = ni * 16 + l16;
        f32x4 acc = o[ni];
#pragma unroll
        for (int nb = 0; nb < 4; ++nb) {
          int ch = (2 * nb + (lq >> 1)) ^ sx;
          short4v bv = *(const short4v*)&Vb_[row * 64 + ch * 8 + ((lq & 1) << 2)];
          acc = mfma_pv(pa[nb], bv, acc);
        }
        o[ni] = acc;
      }
      __syncthreads();
      cur ^= 1;
    }

    float red = lsum;
    red += __shfl_xor(red, 16, 64);
    red += __shfl_xor(red, 32, 64);
    float inv[4];
#pragma unroll
    for (int j = 0; j < 4; ++j) {
      int src = (lane & 48) + ((lane >> 4) & 3) * 4 + j;
      inv[j] = 1.0f / __shfl(red, src, 64);
    }
#pragma unroll
    for (int ni = 0; ni < 4; ++ni) {
      int d = h * 64 + ni * 16 + l16;
#pragma unroll
      for (int j = 0; j < 4; ++j) {
        int s = qbase + lq * 4 + j;
        H[((size_t)(b * SS + s)) * 1024 + d] = f2bf(o[ni][j] * inv[j]);
      }
    }
  }
}

extern "C" void kernel_launch(void* const* d_in, const int* in_sizes, int n_in,
                              void* d_out, int out_size, void* d_ws, size_t ws_size,
                              hipStream_t stream) {
  const float* x    = (const float*)d_in[0];
  const int*   pos  = (const int*)d_in[1];
  const float* Wqkv = (const float*)d_in[2];
  const float* bqkv = (const float*)d_in[3];
  const float* Wo   = (const float*)d_in[4];
  const float* bo   = (const float*)d_in[5];
  float* out = (float*)d_out;

  char* w = (char*)d_ws;
  unsigned short* x_bf    = (unsigned short*)(w + 0);          // 16 MB [8192][1024]
  unsigned short* h_bf    = x_bf;                              // alias (x dead after gemm1)
  unsigned short* wqkv_bf = (unsigned short*)(w + 16777216);   // 6 MB [3072][1024]
  unsigned short* wo_bf   = (unsigned short*)(w + 23068672);   // 2 MB [1024][1024]
  unsigned short* Qb      = (unsigned short*)(w + 25165824);   // 16 MB [64][2048][64]
  unsigned short* Kb      = (unsigned short*)(w + 41943040);   // 16 MB
  unsigned short* Vt      = (unsigned short*)(w + 58720256);   // 16 MB [64][64][2048]
  float* tabc             = (float*)(w + 75497472);            // 1 MB [8192][32]
  float* tabs             = (float*)(w + 76546048);            // 1 MB

  k_cvt<<<8192, 256, 0, stream>>>(x, x_bf, 2097152);
  k_cvt<<<3072, 256, 0, stream>>>(Wqkv, wqkv_bf, 786432);
  k_cvt<<<1024, 256, 0, stream>>>(Wo, wo_bf, 262144);
  k_tab<<<1024, 256, 0, stream>>>(pos, tabc, tabs);
  k_gemm6<1><<<384, 512, 0, stream>>>(x_bf, wqkv_bf, bqkv, Qb, Kb, Vt, tabc, tabs, TOK, 3072, DM);
  k_attn<<<1024, 256, 0, stream>>>(Qb, Kb, Vt, h_bf);
  k_gemm3<0><<<256, 512, 0, stream>>>(h_bf, wo_bf, bo, out, nullptr, nullptr, tabc, tabs, TOK, DM, DM);
}

// Round 12
// 193.567 us; speedup vs baseline: 1.1919x; 1.1919x over previous
//
#include <hip/hip_runtime.h>

#define DEV static __device__ __forceinline__

typedef __attribute__((ext_vector_type(8))) short short8;
typedef __attribute__((ext_vector_type(4))) short short4v;
typedef __attribute__((ext_vector_type(4))) float f32x4;
typedef __attribute__((ext_vector_type(4))) unsigned short ushort4v;
typedef __attribute__((ext_vector_type(4))) float float4v;

#define DM 1024
#define NH 16
#define HD 64
#define SS 2048
#define TOK 8192

DEV unsigned short f2bf(float f) {
  union { float f; unsigned u; } v; v.f = f;
  unsigned r = v.u + 0x7FFFu + ((v.u >> 16) & 1u);
  return (unsigned short)(r >> 16);
}
DEV float bf2f(unsigned short h) {
  union { unsigned u; float f; } v; v.u = ((unsigned)h) << 16;
  return v.f;
}

#define MFMA16x32(a, b, c) __builtin_amdgcn_mfma_f32_16x16x32_bf16((a), (b), (c), 0, 0, 0)

DEV f32x4 mfma_pv(short4v a, short4v b, f32x4 c) {
#if __has_builtin(__builtin_amdgcn_mfma_f32_16x16x16bf16_1k)
  return __builtin_amdgcn_mfma_f32_16x16x16bf16_1k(a, b, c, 0, 0, 0);
#else
  f32x4 d;
  asm("v_mfma_f32_16x16x16_bf16 %0, %1, %2, %3" : "=&v"(d) : "v"(a), "v"(b), "v"(c));
  return d;
#endif
}

DEV void gload_lds16(const unsigned short* g, unsigned short* l) {
  __builtin_amdgcn_global_load_lds(
      (const __attribute__((address_space(1))) void*)g,
      (__attribute__((address_space(3))) void*)l, 16, 0, 0);
}

// ---------------- fp32 -> bf16 convert ----------------
__global__ __launch_bounds__(256) void k_cvt(const float* __restrict__ in,
                                             unsigned short* __restrict__ out, int n4) {
  int i = blockIdx.x * 256 + threadIdx.x;
  if (i >= n4) return;
  float4v v = ((const float4v*)in)[i];
  ushort4v o;
  o[0] = f2bf(v[0]); o[1] = f2bf(v[1]); o[2] = f2bf(v[2]); o[3] = f2bf(v[3]);
  ((ushort4v*)out)[i] = o;
}

// ---------------- RoPE cos/sin table: [B*S][32] ----------------
__global__ __launch_bounds__(256) void k_tab(const int* __restrict__ pos,
                                             float* __restrict__ tc, float* __restrict__ ts) {
  int i = blockIdx.x * 256 + threadIdx.x;   // B*S*32 total
  int t = i >> 5, fi = i & 31;
  float p = (float)pos[t];
  float inv = powf(10000.0f, -(float)fi / 32.0f);
  float a = p * inv;
  float sv, cv;
  sincosf(a, &sv, &cv);
  tc[i] = cv;
  ts[i] = sv;
}

// ---------------- bf16 GEMM, B^T layout, 3-stage counted-vmcnt pipeline -----
// (R6/R10-proven config: BM=256, BN=128, BK=64, 512 thr, 3 rotating buffers,
//  counted vmcnt(6), fragment/XOR LDS 0-conflict, m-chunk XCD swizzle.)
// MODE 0: out0 = fp32 [M][N]
// MODE 1: qkv scatter + FUSED ROPE on Q,K; out2=Vt [b,h,d,s]
template <int MODE>
__global__ __launch_bounds__(512) void k_gemm3(
    const unsigned short* __restrict__ A, const unsigned short* __restrict__ Bm,
    const float* __restrict__ bias, void* __restrict__ out0, void* __restrict__ out1,
    void* __restrict__ out2, const float* __restrict__ tabc,
    const float* __restrict__ tabs, int M, int N, int K) {
  __shared__ __align__(16) unsigned short Abuf[3][256 * 64];   // 96 KB
  __shared__ __align__(16) unsigned short Bbuf[3][128 * 64];   // 48 KB
  const int tid = threadIdx.x;
  const int wid = tid >> 6, lane = tid & 63;
  const int l16 = lane & 15, lq = lane >> 4;
  const int wr = wid >> 1, wc = wid & 1;
  const int r8 = lane >> 3, c8 = lane & 7;    // staging: row-in-octet, chunk
  const int NT = K >> 6;
  const int sx = l16 & 7;                     // read-side swizzle key

  // m-chunk XCD swizzle (R6): xcd = bid&7 owns contiguous m-range, n-fastest.
  const int gx = N >> 7;
  const int nwg = gx * (M >> 8);
  const int chunk = nwg >> 3;
  const int bid = blockIdx.x;
  const int virt = (bid & 7) * chunk + (bid >> 3);
  const int m0 = (virt / gx) << 8;
  const int n0 = (virt % gx) << 7;

#define STAGE_G3(T, BSEL)                                                           \
  {                                                                                 \
    int k0_ = (T) << 6;                                                             \
    unsigned short* ab_ = Abuf[BSEL];                                               \
    unsigned short* bb_ = Bbuf[BSEL];                                               \
    _Pragma("unroll")                                                               \
    for (int i_ = 0; i_ < 4; ++i_) {                                                \
      int c_ = wid * 4 + i_;                                                        \
      gload_lds16(A + (size_t)(m0 + c_ * 8 + r8) * K + k0_ + ((c8 ^ r8) << 3),      \
                  &ab_[c_ * 512]);                                                  \
    }                                                                               \
    _Pragma("unroll")                                                               \
    for (int i_ = 0; i_ < 2; ++i_) {                                                \
      int c_ = wid * 2 + i_;                                                        \
      gload_lds16(Bm + (size_t)(n0 + c_ * 8 + r8) * K + k0_ + ((c8 ^ r8) << 3),     \
                  &bb_[c_ * 512]);                                                  \
    }                                                                               \
  }

  f32x4 acc[4][4];
#pragma unroll
  for (int i = 0; i < 4; i++)
#pragma unroll
    for (int j = 0; j < 4; j++) acc[i][j] = (f32x4){0.f, 0.f, 0.f, 0.f};

  STAGE_G3(0, 0)
  STAGE_G3(1, 1)
  asm volatile("s_waitcnt vmcnt(6)" ::: "memory");
  __builtin_amdgcn_s_barrier();
  __builtin_amdgcn_sched_barrier(0);

  int cb = 0, sb = 2;
  for (int t = 0; t < NT; ++t) {
    if (t + 2 < NT) STAGE_G3(t + 2, sb)
    const unsigned short* Ab = Abuf[cb];
    const unsigned short* Bb = Bbuf[cb];
#pragma unroll
    for (int kk = 0; kk < 2; ++kk) {
      int sw0 = ((kk * 4 + lq) ^ sx) << 3;
      short8 af[4], bfr[4];
#pragma unroll
      for (int mi = 0; mi < 4; ++mi)
        af[mi] = *(const short8*)&Ab[(wr * 64 + mi * 16 + l16) * 64 + sw0];
#pragma unroll
      for (int ni = 0; ni < 4; ++ni)
        bfr[ni] = *(const short8*)&Bb[(wc * 64 + ni * 16 + l16) * 64 + sw0];
#pragma unroll
      for (int mi = 0; mi < 4; ++mi)
#pragma unroll
        for (int ni = 0; ni < 4; ++ni)
          acc[mi][ni] = MFMA16x32(af[mi], bfr[ni], acc[mi][ni]);
    }
    if (t + 1 < NT) {
      if (t + 3 <= NT) {
        asm volatile("s_waitcnt vmcnt(6)" ::: "memory");
      } else {
        asm volatile("s_waitcnt vmcnt(0)" ::: "memory");
      }
      __builtin_amdgcn_s_barrier();
      __builtin_amdgcn_sched_barrier(0);
    }
    cb = (cb == 2) ? 0 : cb + 1;
    sb = (sb == 2) ? 0 : sb + 1;
  }
#undef STAGE_G3

  if (MODE == 0) {
    float* C = (float*)out0;
#pragma unroll
    for (int mi = 0; mi < 4; ++mi) {
      int row = m0 + wr * 64 + mi * 16 + lq * 4;
#pragma unroll
      for (int ni = 0; ni < 4; ++ni) {
        int col = n0 + wc * 64 + ni * 16 + l16;
        float bv = bias[col];
#pragma unroll
        for (int j = 0; j < 4; ++j)
          C[(size_t)(row + j) * N + col] = acc[mi][ni][j] + bv;
      }
    }
  } else {
    unsigned short* Qb = (unsigned short*)out0;
    unsigned short* Kb = (unsigned short*)out1;
    unsigned short* Vt = (unsigned short*)out2;
    int sel0 = n0 >> 10;
#pragma unroll
    for (int mi = 0; mi < 4; ++mi) {
      int row = m0 + wr * 64 + mi * 16 + lq * 4;
#pragma unroll
      for (int ni = 0; ni < 4; ++ni) {
        int col = n0 + wc * 64 + ni * 16 + l16;
        int hh = (col >> 6) & 15;
        int d = col & 63;
        float bv = bias[col];
        if (sel0 < 2) {
          unsigned short* P = sel0 ? Kb : Qb;
          int pfr = d >> 1;
          size_t p = ((size_t)((row >> 11) * NH + hh) * SS + (row & 2047)) * 64 + d;
#pragma unroll
          for (int j = 0; j < 4; ++j) {
            float val = acc[mi][ni][j] + bv;
            float part = __shfl_xor(val, 1, 64);
            int rr = row + j;
            float cv = tabc[((size_t)rr << 5) + pfr];
            float sv = tabs[((size_t)rr << 5) + pfr];
            float outv = (d & 1) ? (part * sv + val * cv)
                                 : (val * cv - part * sv);
            P[p + (size_t)j * 64] = f2bf(outv);
          }
        } else {
          size_t p = ((size_t)((row >> 11) * NH + hh) * 64 + d) * SS + (row & 2047);
          ushort4v o;
#pragma unroll
          for (int j = 0; j < 4; ++j) o[j] = f2bf(acc[mi][ni][j] + bv);
          *(ushort4v*)&Vt[p] = o;
        }
      }
    }
  }
}

// ---------------- causal flash attention, swapped-QK in-register softmax ----
// Q,K: [bh][s][64] bf16 (roped); Vt: [bh][64][s] bf16; H out: [b][s][1024] bf16
// 2048 single-granule blocks (bh = lin&63 keeps each head's K/V on one XCD L2;
// g = 31 - (lin>>6) -> longest blocks dispatch FIRST, stragglers are tiny).
// ~5 blocks/CU resident (LDS 32 KB) -> ~20 waves/CU of cross-block TLP hides
// the per-tile serial chain + staging drain. 4 waves x 16 q-rows.
// Swapped QK^T (mfma(K,Q)) -> P stays in-lane as the PV A-fragment.
// No-max softmax; exp via raw v_exp_f32 (log2e folded); cvt_pk packing.
__global__ __launch_bounds__(256) void k_attn(const unsigned short* __restrict__ Q,
                                              const unsigned short* __restrict__ K,
                                              const unsigned short* __restrict__ Vt,
                                              unsigned short* __restrict__ H) {
  __shared__ __align__(16) unsigned short Kbuf[2 * 4096];
  __shared__ __align__(16) unsigned short Vbuf[2 * 4096];

  int lin = blockIdx.x;          // 2048 blocks
  int bh = lin & 63;
  int g = 31 - (lin >> 6);       // granule 0..31 (64 q-rows), longest first
  int b = bh >> 4, h = bh & 15;
  int wid = threadIdx.x >> 6, lane = threadIdx.x & 63;
  int l16 = lane & 15, lq = lane >> 4;
  int sx = l16 & 7;              // read-side swizzle key (row&7)
  const unsigned short* Qh = Q + (size_t)bh * SS * 64;
  const unsigned short* Kh = K + (size_t)bh * SS * 64;
  const unsigned short* Vh = Vt + (size_t)bh * 64 * SS;

  int qbase = g * 64 + wid * 16;            // this wave's first q-row
  int qrow = qbase + l16;                   // this lane's q-row
  int ntk = g + 1;

  // Q as B-fragments (col=l16 -> q-row)
  short8 aq[2];
  {
    const unsigned short* qp = Qh + (size_t)qrow * 64 + lq * 8;
    aq[0] = *(const short8*)qp;
    aq[1] = *(const short8*)(qp + 32);
  }
  f32x4 o[4];
#pragma unroll
  for (int i = 0; i < 4; ++i) o[i] = (f32x4){0.f, 0.f, 0.f, 0.f};
  float lsum = 0.f;

  // prologue: stage tile 0 into buffer 0 (chunk-XOR-swizzled source)
#pragma unroll
  for (int i = 0; i < 2; ++i) {
    int c = threadIdx.x + (i << 8);
    int row = c >> 3, col = ((c & 7) ^ (row & 7)) << 3;
    gload_lds16(Kh + (size_t)row * 64 + col, &Kbuf[c * 8]);
    gload_lds16(Vh + (size_t)row * SS + col, &Vbuf[c * 8]);
  }
  __syncthreads();

  int cur = 0;
  for (int kt = 0; kt < ntk; ++kt) {
    // issue next tile's staging (overlaps with this tile's compute)
    if (kt + 1 < ntk) {
      int kb1 = (kt + 1) << 6;
      int nb_ = (cur ^ 1) * 4096;
#pragma unroll
      for (int i = 0; i < 2; ++i) {
        int c = threadIdx.x + (i << 8);
        int row = c >> 3, col = ((c & 7) ^ (row & 7)) << 3;
        gload_lds16(Kh + (size_t)(kb1 + row) * 64 + col, &Kbuf[nb_ + c * 8]);
        gload_lds16(Vh + (size_t)row * SS + kb1 + col, &Vbuf[nb_ + c * 8]);
      }
    }
    int kb = kt << 6;
    const unsigned short* Kb_ = &Kbuf[cur * 4096];
    const unsigned short* Vb_ = &Vbuf[cur * 4096];

    // swapped QK^T: sacc[nb] = C[key][q], key = nb*16 + lq*4 + j, q = l16
    f32x4 sacc[4];
#pragma unroll
    for (int nb = 0; nb < 4; ++nb) {
      int r = nb * 16 + l16;
      short8 bk0 = *(const short8*)&Kb_[r * 64 + ((lq ^ sx) << 3)];
      short8 bk1 = *(const short8*)&Kb_[r * 64 + (((4 | lq) ^ sx) << 3)];
      f32x4 z = (f32x4){0.f, 0.f, 0.f, 0.f};
      z = MFMA16x32(bk0, aq[0], z);
      z = MFMA16x32(bk1, aq[1], z);
      sacc[nb] = z;
    }
    // scale (with log2e folded), mask, exp2, accumulate, pack
    float sc[4][4];
#pragma unroll
    for (int nb = 0; nb < 4; ++nb)
#pragma unroll
      for (int j = 0; j < 4; ++j) sc[nb][j] = sacc[nb][j] * 0.18033688f;
    if (kt == g) {   // diagonal tile (wave-uniform branch)
#pragma unroll
      for (int nb = 0; nb < 4; ++nb)
#pragma unroll
        for (int j = 0; j < 4; ++j) {
          int key = kb + nb * 16 + lq * 4 + j;
          if (key > qrow) sc[nb][j] = -1e30f;
        }
    }
    short4v pa[4];
#pragma unroll
    for (int nb = 0; nb < 4; ++nb) {
      float pv[4];
#pragma unroll
      for (int j = 0; j < 4; ++j) {
        float e;
        asm("v_exp_f32 %0, %1" : "=v"(e) : "v"(sc[nb][j]));
        lsum += e;
        pv[j] = e;
      }
      union { unsigned u[2]; short4v s4; } pk;
      asm("v_cvt_pk_bf16_f32 %0, %1, %2" : "=v"(pk.u[0]) : "v"(pv[0]), "v"(pv[1]));
      asm("v_cvt_pk_bf16_f32 %0, %1, %2" : "=v"(pk.u[1]) : "v"(pv[2]), "v"(pv[3]));
      pa[nb] = pk.s4;
    }
    // PV: O[q][d] += P[q][k] * V[k][d]; V from Vt rows (d on l16)
#pragma unroll
    for (int ni = 0; ni < 4; ++ni) {
      int row = ni * 16 + l16;
      f32x4 acc = o[ni];
#pragma unroll
      for (int nb = 0; nb < 4; ++nb) {
        int ch = (2 * nb + (lq >> 1)) ^ sx;
        short4v bv = *(const short4v*)&Vb_[row * 64 + ch * 8 + ((lq & 1) << 2)];
        acc = mfma_pv(pa[nb], bv, acc);
      }
      o[ni] = acc;
    }
    __syncthreads();   // drains staging loads; protects buffer swap
    cur ^= 1;
  }

  // reduce lsum over the 4 lq-lanes, redistribute to output rows
  float red = lsum;
  red += __shfl_xor(red, 16, 64);
  red += __shfl_xor(red, 32, 64);
  float inv[4];
#pragma unroll
  for (int j = 0; j < 4; ++j) {
    int src = (lane & 48) + ((lane >> 4) & 3) * 4 + j;
    inv[j] = 1.0f / __shfl(red, src, 64);
  }
#pragma unroll
  for (int ni = 0; ni < 4; ++ni) {
    int d = h * 64 + ni * 16 + l16;
#pragma unroll
    for (int j = 0; j < 4; ++j) {
      int s = qbase + lq * 4 + j;
      H[((size_t)(b * SS + s)) * 1024 + d] = f2bf(o[ni][j] * inv[j]);
    }
  }
}

extern "C" void kernel_launch(void* const* d_in, const int* in_sizes, int n_in,
                              void* d_out, int out_size, void* d_ws, size_t ws_size,
                              hipStream_t stream) {
  const float* x    = (const float*)d_in[0];
  const int*   pos  = (const int*)d_in[1];
  const float* Wqkv = (const float*)d_in[2];
  const float* bqkv = (const float*)d_in[3];
  const float* Wo   = (const float*)d_in[4];
  const float* bo   = (const float*)d_in[5];
  float* out = (float*)d_out;

  char* w = (char*)d_ws;
  unsigned short* x_bf    = (unsigned short*)(w + 0);          // 16 MB [8192][1024]
  unsigned short* h_bf    = x_bf;                              // alias (x dead after gemm1)
  unsigned short* wqkv_bf = (unsigned short*)(w + 16777216);   // 6 MB [3072][1024]
  unsigned short* wo_bf   = (unsigned short*)(w + 23068672);   // 2 MB [1024][1024]
  unsigned short* Qb      = (unsigned short*)(w + 25165824);   // 16 MB [64][2048][64]
  unsigned short* Kb      = (unsigned short*)(w + 41943040);   // 16 MB
  unsigned short* Vt      = (unsigned short*)(w + 58720256);   // 16 MB [64][64][2048]
  float* tabc             = (float*)(w + 75497472);            // 1 MB [8192][32]
  float* tabs             = (float*)(w + 76546048);            // 1 MB

  k_cvt<<<8192, 256, 0, stream>>>(x, x_bf, 2097152);
  k_cvt<<<3072, 256, 0, stream>>>(Wqkv, wqkv_bf, 786432);
  k_cvt<<<1024, 256, 0, stream>>>(Wo, wo_bf, 262144);
  k_tab<<<1024, 256, 0, stream>>>(pos, tabc, tabs);
  k_gemm3<1><<<768, 512, 0, stream>>>(x_bf, wqkv_bf, bqkv, Qb, Kb, Vt, tabc, tabs, TOK, 3072, DM);
  k_attn<<<2048, 256, 0, stream>>>(Qb, Kb, Vt, h_bf);
  k_gemm3<0><<<256, 512, 0, stream>>>(h_bf, wo_bf, bo, out, nullptr, nullptr, tabc, tabs, TOK, DM, DM);
}

// Round 13
// 186.743 us; speedup vs baseline: 1.2354x; 1.0365x over previous
//
#include <hip/hip_runtime.h>

#define DEV static __device__ __forceinline__

typedef __attribute__((ext_vector_type(8))) short short8;
typedef __attribute__((ext_vector_type(4))) short short4v;
typedef __attribute__((ext_vector_type(4))) float f32x4;
typedef __attribute__((ext_vector_type(4))) unsigned short ushort4v;
typedef __attribute__((ext_vector_type(4))) float float4v;

#define DM 1024
#define NH 16
#define HD 64
#define SS 2048
#define TOK 8192

DEV unsigned short f2bf(float f) {
  union { float f; unsigned u; } v; v.f = f;
  unsigned r = v.u + 0x7FFFu + ((v.u >> 16) & 1u);
  return (unsigned short)(r >> 16);
}
DEV float bf2f(unsigned short h) {
  union { unsigned u; float f; } v; v.u = ((unsigned)h) << 16;
  return v.f;
}

#define MFMA16x32(a, b, c) __builtin_amdgcn_mfma_f32_16x16x32_bf16((a), (b), (c), 0, 0, 0)

DEV f32x4 mfma_pv(short4v a, short4v b, f32x4 c) {
#if __has_builtin(__builtin_amdgcn_mfma_f32_16x16x16bf16_1k)
  return __builtin_amdgcn_mfma_f32_16x16x16bf16_1k(a, b, c, 0, 0, 0);
#else
  f32x4 d;
  asm("v_mfma_f32_16x16x16_bf16 %0, %1, %2, %3" : "=&v"(d) : "v"(a), "v"(b), "v"(c));
  return d;
#endif
}

DEV void gload_lds16(const unsigned short* g, unsigned short* l) {
  __builtin_amdgcn_global_load_lds(
      (const __attribute__((address_space(1))) void*)g,
      (__attribute__((address_space(3))) void*)l, 16, 0, 0);
}

// ---------------- fp32 -> bf16 convert ----------------
__global__ __launch_bounds__(256) void k_cvt(const float* __restrict__ in,
                                             unsigned short* __restrict__ out, int n4) {
  int i = blockIdx.x * 256 + threadIdx.x;
  if (i >= n4) return;
  float4v v = ((const float4v*)in)[i];
  ushort4v o;
  o[0] = f2bf(v[0]); o[1] = f2bf(v[1]); o[2] = f2bf(v[2]); o[3] = f2bf(v[3]);
  ((ushort4v*)out)[i] = o;
}

// ---------------- RoPE cos/sin table: [B*S][32] ----------------
__global__ __launch_bounds__(256) void k_tab(const int* __restrict__ pos,
                                             float* __restrict__ tc, float* __restrict__ ts) {
  int i = blockIdx.x * 256 + threadIdx.x;   // B*S*32 total
  int t = i >> 5, fi = i & 31;
  float p = (float)pos[t];
  float inv = powf(10000.0f, -(float)fi / 32.0f);
  float a = p * inv;
  float sv, cv;
  sincosf(a, &sv, &cv);
  tc[i] = cv;
  ts[i] = sv;
}

// ---------------- bf16 GEMM, B^T layout, 3-stage counted-vmcnt pipeline -----
// (R6/R10-proven config: BM=256, BN=128, BK=64, 512 thr, 3 rotating buffers,
//  counted vmcnt(6), fragment/XOR LDS 0-conflict, m-chunk XCD swizzle.)
// MODE 0: out0 = fp32 [M][N]
// MODE 1: qkv scatter + FUSED ROPE on Q,K; out2=Vt [b,h,d,s]
template <int MODE>
__global__ __launch_bounds__(512) void k_gemm3(
    const unsigned short* __restrict__ A, const unsigned short* __restrict__ Bm,
    const float* __restrict__ bias, void* __restrict__ out0, void* __restrict__ out1,
    void* __restrict__ out2, const float* __restrict__ tabc,
    const float* __restrict__ tabs, int M, int N, int K) {
  __shared__ __align__(16) unsigned short Abuf[3][256 * 64];   // 96 KB
  __shared__ __align__(16) unsigned short Bbuf[3][128 * 64];   // 48 KB
  const int tid = threadIdx.x;
  const int wid = tid >> 6, lane = tid & 63;
  const int l16 = lane & 15, lq = lane >> 4;
  const int wr = wid >> 1, wc = wid & 1;
  const int r8 = lane >> 3, c8 = lane & 7;    // staging: row-in-octet, chunk
  const int NT = K >> 6;
  const int sx = l16 & 7;                     // read-side swizzle key

  // m-chunk XCD swizzle (R6): xcd = bid&7 owns contiguous m-range, n-fastest.
  const int gx = N >> 7;
  const int nwg = gx * (M >> 8);
  const int chunk = nwg >> 3;
  const int bid = blockIdx.x;
  const int virt = (bid & 7) * chunk + (bid >> 3);
  const int m0 = (virt / gx) << 8;
  const int n0 = (virt % gx) << 7;

#define STAGE_G3(T, BSEL)                                                           \
  {                                                                                 \
    int k0_ = (T) << 6;                                                             \
    unsigned short* ab_ = Abuf[BSEL];                                               \
    unsigned short* bb_ = Bbuf[BSEL];                                               \
    _Pragma("unroll")                                                               \
    for (int i_ = 0; i_ < 4; ++i_) {                                                \
      int c_ = wid * 4 + i_;                                                        \
      gload_lds16(A + (size_t)(m0 + c_ * 8 + r8) * K + k0_ + ((c8 ^ r8) << 3),      \
                  &ab_[c_ * 512]);                                                  \
    }                                                                               \
    _Pragma("unroll")                                                               \
    for (int i_ = 0; i_ < 2; ++i_) {                                                \
      int c_ = wid * 2 + i_;                                                        \
      gload_lds16(Bm + (size_t)(n0 + c_ * 8 + r8) * K + k0_ + ((c8 ^ r8) << 3),     \
                  &bb_[c_ * 512]);                                                  \
    }                                                                               \
  }

  f32x4 acc[4][4];
#pragma unroll
  for (int i = 0; i < 4; i++)
#pragma unroll
    for (int j = 0; j < 4; j++) acc[i][j] = (f32x4){0.f, 0.f, 0.f, 0.f};

  STAGE_G3(0, 0)
  STAGE_G3(1, 1)
  asm volatile("s_waitcnt vmcnt(6)" ::: "memory");
  __builtin_amdgcn_s_barrier();
  __builtin_amdgcn_sched_barrier(0);

  int cb = 0, sb = 2;
  for (int t = 0; t < NT; ++t) {
    if (t + 2 < NT) STAGE_G3(t + 2, sb)
    const unsigned short* Ab = Abuf[cb];
    const unsigned short* Bb = Bbuf[cb];
#pragma unroll
    for (int kk = 0; kk < 2; ++kk) {
      int sw0 = ((kk * 4 + lq) ^ sx) << 3;
      short8 af[4], bfr[4];
#pragma unroll
      for (int mi = 0; mi < 4; ++mi)
        af[mi] = *(const short8*)&Ab[(wr * 64 + mi * 16 + l16) * 64 + sw0];
#pragma unroll
      for (int ni = 0; ni < 4; ++ni)
        bfr[ni] = *(const short8*)&Bb[(wc * 64 + ni * 16 + l16) * 64 + sw0];
#pragma unroll
      for (int mi = 0; mi < 4; ++mi)
#pragma unroll
        for (int ni = 0; ni < 4; ++ni)
          acc[mi][ni] = MFMA16x32(af[mi], bfr[ni], acc[mi][ni]);
    }
    if (t + 1 < NT) {
      if (t + 3 <= NT) {
        asm volatile("s_waitcnt vmcnt(6)" ::: "memory");
      } else {
        asm volatile("s_waitcnt vmcnt(0)" ::: "memory");
      }
      __builtin_amdgcn_s_barrier();
      __builtin_amdgcn_sched_barrier(0);
    }
    cb = (cb == 2) ? 0 : cb + 1;
    sb = (sb == 2) ? 0 : sb + 1;
  }
#undef STAGE_G3

  if (MODE == 0) {
    float* C = (float*)out0;
#pragma unroll
    for (int mi = 0; mi < 4; ++mi) {
      int row = m0 + wr * 64 + mi * 16 + lq * 4;
#pragma unroll
      for (int ni = 0; ni < 4; ++ni) {
        int col = n0 + wc * 64 + ni * 16 + l16;
        float bv = bias[col];
#pragma unroll
        for (int j = 0; j < 4; ++j)
          C[(size_t)(row + j) * N + col] = acc[mi][ni][j] + bv;
      }
    }
  } else {
    unsigned short* Qb = (unsigned short*)out0;
    unsigned short* Kb = (unsigned short*)out1;
    unsigned short* Vt = (unsigned short*)out2;
    int sel0 = n0 >> 10;
#pragma unroll
    for (int mi = 0; mi < 4; ++mi) {
      int row = m0 + wr * 64 + mi * 16 + lq * 4;
#pragma unroll
      for (int ni = 0; ni < 4; ++ni) {
        int col = n0 + wc * 64 + ni * 16 + l16;
        int hh = (col >> 6) & 15;
        int d = col & 63;
        float bv = bias[col];
        if (sel0 < 2) {
          unsigned short* P = sel0 ? Kb : Qb;
          int pfr = d >> 1;
          size_t p = ((size_t)((row >> 11) * NH + hh) * SS + (row & 2047)) * 64 + d;
#pragma unroll
          for (int j = 0; j < 4; ++j) {
            float val = acc[mi][ni][j] + bv;
            float part = __shfl_xor(val, 1, 64);
            int rr = row + j;
            float cv = tabc[((size_t)rr << 5) + pfr];
            float sv = tabs[((size_t)rr << 5) + pfr];
            float outv = (d & 1) ? (part * sv + val * cv)
                                 : (val * cv - part * sv);
            P[p + (size_t)j * 64] = f2bf(outv);
          }
        } else {
          size_t p = ((size_t)((row >> 11) * NH + hh) * 64 + d) * SS + (row & 2047);
          ushort4v o;
#pragma unroll
          for (int j = 0; j < 4; ++j) o[j] = f2bf(acc[mi][ni][j] + bv);
          *(ushort4v*)&Vt[p] = o;
        }
      }
    }
  }
}

// ---------------- causal flash attention, swapped-QK in-register softmax ----
// Q,K: [bh][s][64] bf16 (roped); Vt: [bh][64][s] bf16; H out: [b][s][1024] bf16
// q-granule = 128 rows (8 waves x 16 q-rows, 512 threads) -> K/V staging
// traffic halves vs 64-row granules (attn is staging-BW bound at ~37 B/cy/CU).
// 1024 blocks = 64 heads x 16 granules; g = 15 - (lin>>6) -> longest first.
// Waves skip compute (not barriers) past their diagonal (kt <= ktmax).
// Swapped QK^T (mfma(K,Q)) -> P stays in-lane as the PV A-fragment.
// No-max softmax; exp via raw v_exp_f32 (log2e folded); cvt_pk packing.
__global__ __launch_bounds__(512) void k_attn(const unsigned short* __restrict__ Q,
                                              const unsigned short* __restrict__ K,
                                              const unsigned short* __restrict__ Vt,
                                              unsigned short* __restrict__ H) {
  __shared__ __align__(16) unsigned short Kbuf[2 * 4096];
  __shared__ __align__(16) unsigned short Vbuf[2 * 4096];

  int lin = blockIdx.x;          // 1024 blocks
  int bh = lin & 63;
  int g = 15 - (lin >> 6);       // granule 0..15 (128 q-rows), longest first
  int b = bh >> 4, h = bh & 15;
  int tid = threadIdx.x;
  int wid = tid >> 6, lane = tid & 63;
  int l16 = lane & 15, lq = lane >> 4;
  int sx = l16 & 7;              // read-side swizzle key (row&7)
  const unsigned short* Qh = Q + (size_t)bh * SS * 64;
  const unsigned short* Kh = K + (size_t)bh * SS * 64;
  const unsigned short* Vh = Vt + (size_t)bh * 64 * SS;

  int qbase = g * 128 + wid * 16;           // this wave's first q-row
  int qrow = qbase + l16;                   // this lane's q-row
  int ktmax = (qbase + 15) >> 6;            // last (diagonal) tile for this wave
  int ntk = 2 * g + 2;                      // tiles staged by the block

  // Q as B-fragments (col=l16 -> q-row)
  short8 aq[2];
  {
    const unsigned short* qp = Qh + (size_t)qrow * 64 + lq * 8;
    aq[0] = *(const short8*)qp;
    aq[1] = *(const short8*)(qp + 32);
  }
  f32x4 o[4];
#pragma unroll
  for (int i = 0; i < 4; ++i) o[i] = (f32x4){0.f, 0.f, 0.f, 0.f};
  float lsum = 0.f;

  // prologue: stage tile 0 into buffer 0 (chunk-XOR-swizzled source)
  // 512 threads cover the 512 16B-cells of each 8KB tile exactly once.
  {
    int c = tid;
    int row = c >> 3, col = ((c & 7) ^ (row & 7)) << 3;
    gload_lds16(Kh + (size_t)row * 64 + col, &Kbuf[c * 8]);
    gload_lds16(Vh + (size_t)row * SS + col, &Vbuf[c * 8]);
  }
  __syncthreads();

  int cur = 0;
  for (int kt = 0; kt < ntk; ++kt) {
    // issue next tile's staging (overlaps with this tile's compute)
    if (kt + 1 < ntk) {
      int kb1 = (kt + 1) << 6;
      int nb_ = (cur ^ 1) * 4096;
      int c = tid;
      int row = c >> 3, col = ((c & 7) ^ (row & 7)) << 3;
      gload_lds16(Kh + (size_t)(kb1 + row) * 64 + col, &Kbuf[nb_ + c * 8]);
      gload_lds16(Vh + (size_t)row * SS + kb1 + col, &Vbuf[nb_ + c * 8]);
    }
    if (kt <= ktmax) {
      int kb = kt << 6;
      const unsigned short* Kb_ = &Kbuf[cur * 4096];
      const unsigned short* Vb_ = &Vbuf[cur * 4096];

      // swapped QK^T: sacc[nb] = C[key][q], key = nb*16 + lq*4 + j, q = l16
      f32x4 sacc[4];
#pragma unroll
      for (int nb = 0; nb < 4; ++nb) {
        int r = nb * 16 + l16;
        short8 bk0 = *(const short8*)&Kb_[r * 64 + ((lq ^ sx) << 3)];
        short8 bk1 = *(const short8*)&Kb_[r * 64 + (((4 | lq) ^ sx) << 3)];
        f32x4 z = (f32x4){0.f, 0.f, 0.f, 0.f};
        z = MFMA16x32(bk0, aq[0], z);
        z = MFMA16x32(bk1, aq[1], z);
        sacc[nb] = z;
      }
      // scale (with log2e folded), mask, exp2, accumulate, pack
      float sc[4][4];
#pragma unroll
      for (int nb = 0; nb < 4; ++nb)
#pragma unroll
        for (int j = 0; j < 4; ++j) sc[nb][j] = sacc[nb][j] * 0.18033688f;
      if (kt == ktmax) {   // diagonal tile (wave-uniform branch)
#pragma unroll
        for (int nb = 0; nb < 4; ++nb)
#pragma unroll
          for (int j = 0; j < 4; ++j) {
            int key = kb + nb * 16 + lq * 4 + j;
            if (key > qrow) sc[nb][j] = -1e30f;
          }
      }
      short4v pa[4];
#pragma unroll
      for (int nb = 0; nb < 4; ++nb) {
        float pv[4];
#pragma unroll
        for (int j = 0; j < 4; ++j) {
          float e;
          asm("v_exp_f32 %0, %1" : "=v"(e) : "v"(sc[nb][j]));
          lsum += e;
          pv[j] = e;
        }
        union { unsigned u[2]; short4v s4; } pk;
        asm("v_cvt_pk_bf16_f32 %0, %1, %2" : "=v"(pk.u[0]) : "v"(pv[0]), "v"(pv[1]));
        asm("v_cvt_pk_bf16_f32 %0, %1, %2" : "=v"(pk.u[1]) : "v"(pv[2]), "v"(pv[3]));
        pa[nb] = pk.s4;
      }
      // PV: O[q][d] += P[q][k] * V[k][d]; V from Vt rows (d on l16)
#pragma unroll
      for (int ni = 0; ni < 4; ++ni) {
        int row = ni * 16 + l16;
        f32x4 acc = o[ni];
#pragma unroll
        for (int nb = 0; nb < 4; ++nb) {
          int ch = (2 * nb + (lq >> 1)) ^ sx;
          short4v bv = *(const short4v*)&Vb_[row * 64 + ch * 8 + ((lq & 1) << 2)];
          acc = mfma_pv(pa[nb], bv, acc);
        }
        o[ni] = acc;
      }
    }
    __syncthreads();   // drains staging loads; protects buffer swap
    cur ^= 1;
  }

  // reduce lsum over the 4 lq-lanes, redistribute to output rows
  float red = lsum;
  red += __shfl_xor(red, 16, 64);
  red += __shfl_xor(red, 32, 64);
  float inv[4];
#pragma unroll
  for (int j = 0; j < 4; ++j) {
    int src = (lane & 48) + ((lane >> 4) & 3) * 4 + j;
    inv[j] = 1.0f / __shfl(red, src, 64);
  }
#pragma unroll
  for (int ni = 0; ni < 4; ++ni) {
    int d = h * 64 + ni * 16 + l16;
#pragma unroll
    for (int j = 0; j < 4; ++j) {
      int s = qbase + lq * 4 + j;
      H[((size_t)(b * SS + s)) * 1024 + d] = f2bf(o[ni][j] * inv[j]);
    }
  }
}

extern "C" void kernel_launch(void* const* d_in, const int* in_sizes, int n_in,
                              void* d_out, int out_size, void* d_ws, size_t ws_size,
                              hipStream_t stream) {
  const float* x    = (const float*)d_in[0];
  const int*   pos  = (const int*)d_in[1];
  const float* Wqkv = (const float*)d_in[2];
  const float* bqkv = (const float*)d_in[3];
  const float* Wo   = (const float*)d_in[4];
  const float* bo   = (const float*)d_in[5];
  float* out = (float*)d_out;

  char* w = (char*)d_ws;
  unsigned short* x_bf    = (unsigned short*)(w + 0);          // 16 MB [8192][1024]
  unsigned short* h_bf    = x_bf;                              // alias (x dead after gemm1)
  unsigned short* wqkv_bf = (unsigned short*)(w + 16777216);   // 6 MB [3072][1024]
  unsigned short* wo_bf   = (unsigned short*)(w + 23068672);   // 2 MB [1024][1024]
  unsigned short* Qb      = (unsigned short*)(w + 25165824);   // 16 MB [64][2048][64]
  unsigned short* Kb      = (unsigned short*)(w + 41943040);   // 16 MB
  unsigned short* Vt      = (unsigned short*)(w + 58720256);   // 16 MB [64][64][2048]
  float* tabc             = (float*)(w + 75497472);            // 1 MB [8192][32]
  float* tabs             = (float*)(w + 76546048);            // 1 MB

  k_cvt<<<8192, 256, 0, stream>>>(x, x_bf, 2097152);
  k_cvt<<<3072, 256, 0, stream>>>(Wqkv, wqkv_bf, 786432);
  k_cvt<<<1024, 256, 0, stream>>>(Wo, wo_bf, 262144);
  k_tab<<<1024, 256, 0, stream>>>(pos, tabc, tabs);
  k_gemm3<1><<<768, 512, 0, stream>>>(x_bf, wqkv_bf, bqkv, Qb, Kb, Vt, tabc, tabs, TOK, 3072, DM);
  k_attn<<<1024, 512, 0, stream>>>(Qb, Kb, Vt, h_bf);
  k_gemm3<0><<<256, 512, 0, stream>>>(h_bf, wo_bf, bo, out, nullptr, nullptr, tabc, tabs, TOK, DM, DM);
}